// Round 10
// baseline (21.223 us; speedup 1.0000x reference)
//
#include <hip/hip_runtime.h>

// BSEC_RNN: B=4096, T=2048, I=1, H=2, O=1.
//   h[t] = tanh(W_ih*x[t] + b_ih + b_hh + W_hh @ h[t-1]),  h[-1] = 0
//   out[t] = fc_w[0]*x[t] + fc_w[1]*h0[t] + fc_w[2]*h1[t] + fc_b
//
// Parallel-in-time (validated r2-r8, absmax = fp32 baseline): CHUNK=32,
// WARM=32 from h=0. Block = 4 waves x [64 seqs, 4 chunks], 40KB LDS,
// 4 blocks/CU = 16 waves/CU (all 4096 wave-items resident: ONE generation).
//
// r10 = r9 (wave-role phase shifting) + race fix. r9's bug: for cg==0,
// wave 1's OWR slots [8,16) are its OUTPUT groups (warm = [0,8)), and
// groups [8,16) are wave 2's warm-read window (cg==0 mapping) -> P3 race.
// Fix: OWR base qb = (cg==0 && w==1) ? 32 : w*8. Groups [32,40) are spare
// in cg==0 blocks (only 32 groups staged). Wave 0's base [0,8) is safe
// (waves 2-3 never read groups <8 under cg==0).
//
// Phases:
//   P1: all 256 thr stage x groups [0,24)
//   P2: waves 0-1 COMPUTE || waves 2-3 stage groups [24,40)   (disjoint LDS)
//   P3: waves 0-1 OWR+STORE (safe slots) || waves 2-3 COMPUTE
//   P4: waves 2-3 OWR+STORE
// All barriers uniform. LDS layout + packed math validated r6.

typedef float f32x2 __attribute__((ext_vector_type(2)));
typedef float f32x4 __attribute__((ext_vector_type(4)));

constexpr int T_LEN   = 2048;
constexpr int CHUNK   = 32;
constexpr int WARM    = 32;
constexpr int THREADS = 256;
constexpr int OSPAN   = 128;               // 4 chunks * 32
constexpr int SPAN    = OSPAN + WARM;      // 160 floats/seq staged (cg>0)
constexpr int NCG     = T_LEN / OSPAN;     // 16 chunk-groups

static __device__ inline float EXP2F(float x){ float r; asm("v_exp_f32 %0, %1":"=v"(r):"v"(x)); return r; }
static __device__ inline float RCPF(float x){ float r; asm("v_rcp_f32 %0, %1":"=v"(r):"v"(x)); return r; }
static __device__ inline f32x2 mk2(float a, float b){ f32x2 t; t.x=a; t.y=b; return t; }

#define PK_FMA_B0(d, s0, s1, s2)                                          \
    asm("v_pk_fma_f32 %0, %1, %2, %3 op_sel:[0,0,0] op_sel_hi:[0,1,1]"    \
        : "=v"(d) : "v"(s0), "v"(s1), "v"(s2))
#define PK_FMA_B1(d, s0, s1, s2)                                          \
    asm("v_pk_fma_f32 %0, %1, %2, %3 op_sel:[1,0,0] op_sel_hi:[1,1,1]"    \
        : "=v"(d) : "v"(s0), "v"(s1), "v"(s2))
#define PK_ADD(d, s0, s1)                                                 \
    asm("v_pk_add_f32 %0, %1, %2" : "=v"(d) : "v"(s0), "v"(s1))

#define PSTEP_CORE(bb)                                                    \
    do {                                                                  \
        f32x2 q_, p_, e_, d_;                                             \
        PK_FMA_B1(q_, rr, mm1, (bb));                                     \
        PK_FMA_B0(p_, rr, mm0, q_);                                       \
        e_.x = EXP2F(p_.x); e_.y = EXP2F(p_.y);                           \
        PK_ADD(d_, e_, ones);                                             \
        rr.x = RCPF(d_.x); rr.y = RCPF(d_.y);                             \
    } while (0)

#define WSTEP_LO(xp2) do { f32x2 b_; PK_FMA_B0(b_, (xp2), aa, cc); PSTEP_CORE(b_); } while (0)
#define WSTEP_HI(xp2) do { f32x2 b_; PK_FMA_B1(b_, (xp2), aa, cc); PSTEP_CORE(b_); } while (0)
#define OSTEP_LO(xp2, ok) do { WSTEP_LO(xp2); (ok) = fmaf(rr.y, g2, fmaf(rr.x, g1, fmaf((xp2).x, f0, fb))); } while (0)
#define OSTEP_HI(xp2, ok) do { WSTEP_HI(xp2); (ok) = fmaf(rr.y, g2, fmaf(rr.x, g1, fmaf((xp2).y, f0, fb))); } while (0)

#define OQ(oo)                                                            \
    do {                                                                  \
        int A_ = q * 256 + (((l ^ q) & 63) << 1);                         \
        f32x2 xa_ = *(const f32x2*)&lx[A_];                               \
        f32x2 xb_ = *(const f32x2*)&lx[A_ + 128];                         \
        OSTEP_LO(xa_, oo.x); OSTEP_HI(xa_, oo.y);                         \
        OSTEP_LO(xb_, oo.z); OSTEP_HI(xb_, oo.w);                         \
        ++q;                                                              \
    } while (0)

// Compute this thread's wave-item (warm + 8 output groups into o0..o7).
#define COMPUTE_REGS()                                                    \
    do {                                                                  \
        int q, warm_q;                                                    \
        if (cg == 0) {                                                    \
            int gt = w * CHUNK - WARM; if (gt < 0) gt = 0;                \
            q = gt >> 2; warm_q = (w * CHUNK - gt) >> 2;                  \
        } else {                                                          \
            q = w * 8; warm_q = 8;                                        \
        }                                                                 \
        f32x2 rr = mk2(0.5f, 0.5f);                                       \
        _Pragma("unroll 2")                                               \
        for (int i = 0; i < warm_q; ++i, ++q) {                           \
            int A_ = q * 256 + (((l ^ q) & 63) << 1);                     \
            f32x2 xa_ = *(const f32x2*)&lx[A_];                           \
            f32x2 xb_ = *(const f32x2*)&lx[A_ + 128];                     \
            WSTEP_LO(xa_); WSTEP_HI(xa_); WSTEP_LO(xb_); WSTEP_HI(xb_);   \
        }                                                                 \
        OQ(o0); OQ(o1); OQ(o2); OQ(o3); OQ(o4); OQ(o5); OQ(o6); OQ(o7);  \
    } while (0)

// OWR into safe LDS slots [qb, qb+8), then same-wave readback + coalesced
// NT store. qb chosen so concurrent computing waves never read those slots:
//   cg>0:  qb = w*8 (own warm slots; waves 2-3 windows are [16,40))
//   cg==0: wave0 qb=0 (waves 2-3 read [8,32)); wave1 qb=32 (spare groups)
#define OWR_STORE()                                                       \
    do {                                                                  \
        const int qb = (cg == 0 && w == 1) ? 32 : w * 8;                  \
        _Pragma("unroll")                                                 \
        for (int j = 0; j < 8; ++j) {                                     \
            f32x4 oo = (j==0)?o0:(j==1)?o1:(j==2)?o2:(j==3)?o3:           \
                       (j==4)?o4:(j==5)?o5:(j==6)?o6:o7;                  \
            int qo = qb + j;                                              \
            int Ao = qo * 256 + (((l ^ qo) & 63) << 1);                   \
            *(f32x2*)&lx[Ao]       = mk2(oo.x, oo.y);                     \
            *(f32x2*)&lx[Ao + 128] = mk2(oo.z, oo.w);                     \
        }                                                                 \
        float* og = out + (size_t)(sg * 64) * T_LEN + cg * OSPAN;         \
        _Pragma("unroll")                                                 \
        for (int k = 0; k < 8; ++k) {                                     \
            int idx = k * 64 + l;                                         \
            int r_ = idx >> 3;                                            \
            int jj = idx & 7;                                             \
            int qg = qb + jj;                                             \
            int c_ = w * 8 + jj;                                          \
            int A_ = qg * 256 + (((r_ ^ qg) & 63) << 1);                  \
            f32x2 lo_ = *(const f32x2*)&lx[A_];                           \
            f32x2 hi_ = *(const f32x2*)&lx[A_ + 128];                     \
            f32x4 v_; v_.x = lo_.x; v_.y = lo_.y; v_.z = hi_.x; v_.w = hi_.y; \
            __builtin_nontemporal_store(v_,                               \
                (f32x4*)(og + (size_t)r_ * T_LEN + c_ * 4));              \
        }                                                                 \
    } while (0)

__global__ __launch_bounds__(THREADS, 4) void rnn_stag(
    const float* __restrict__ x,
    const float* __restrict__ W_ih,
    const float* __restrict__ W_hh,
    const float* __restrict__ b_ih,
    const float* __restrict__ b_hh,
    const float* __restrict__ fc_w,
    const float* __restrict__ fc_b,
    float* __restrict__ out)
{
    __shared__ float lx[SPAN * 64];       // 40 KB = 40 f4-groups

    const int sg  = blockIdx.x >> 4;      // sequence group (64 seqs)
    const int cg  = blockIdx.x & (NCG - 1);
    const int tid = threadIdx.x;
    const int w   = tid >> 6, l = tid & 63;
    const bool hiwave = (tid >= 128);     // waves 2,3

    const int tlo = cg ? cg * OSPAN - WARM : 0;
    const float* xg = x + (size_t)(sg * 64) * T_LEN + tlo;

    // ---- P1: all threads stage f4-groups [0, 24) ----
    #pragma unroll
    for (int k = 0; k < 6; ++k) {
        int idx = k * THREADS + tid;      // < 1536 = 64 rows x 24 cols
        int r_ = idx / 24, c_ = idx - r_ * 24;
        f32x4 v = *(const f32x4*)(xg + (size_t)r_ * T_LEN + c_ * 4);
        int A_ = c_ * 256 + (((r_ ^ c_) & 63) << 1);
        *(f32x2*)&lx[A_]       = mk2(v.x, v.y);
        *(f32x2*)&lx[A_ + 128] = mk2(v.z, v.w);
    }

    // ---- Coefficients (r-trick folding, s = 2*log2(e)) ----
    const float s2 = 2.0f * 1.44269504088896340736f;
    const float W00 = W_hh[0], W01 = W_hh[1], W10 = W_hh[2], W11 = W_hh[3];
    const f32x2 aa  = mk2(W_ih[0] * s2, W_ih[1] * s2);
    const f32x2 cc  = mk2((b_ih[0] + b_hh[0] + W00 + W01) * s2,
                          (b_ih[1] + b_hh[1] + W10 + W11) * s2);
    const f32x2 mm0 = mk2(-2.0f * s2 * W00, -2.0f * s2 * W10);
    const f32x2 mm1 = mk2(-2.0f * s2 * W01, -2.0f * s2 * W11);
    const f32x2 ones = mk2(1.0f, 1.0f);
    const float f0 = fc_w[0];
    const float g1 = -2.0f * fc_w[1], g2 = -2.0f * fc_w[2];
    const float fb = fc_b[0] + fc_w[1] + fc_w[2];

    __syncthreads();                      // bar1: groups [0,24) visible

    f32x4 o0, o1, o2, o3, o4, o5, o6, o7;

    // ---- P2: waves 0-1 compute; waves 2-3 stage groups [24, span) ----
    if (hiwave) {
        const int tid2 = tid & 127;
        if (cg) {
            #pragma unroll
            for (int k = 0; k < 8; ++k) {   // 16 cols x 64 rows
                int idx = k * 128 + tid2;
                int r_ = idx >> 4, c_ = 24 + (idx & 15);
                f32x4 v = *(const f32x4*)(xg + (size_t)r_ * T_LEN + c_ * 4);
                int A_ = c_ * 256 + (((r_ ^ c_) & 63) << 1);
                *(f32x2*)&lx[A_]       = mk2(v.x, v.y);
                *(f32x2*)&lx[A_ + 128] = mk2(v.z, v.w);
            }
        } else {
            #pragma unroll
            for (int k = 0; k < 4; ++k) {   // 8 cols x 64 rows
                int idx = k * 128 + tid2;
                int r_ = idx >> 3, c_ = 24 + (idx & 7);
                f32x4 v = *(const f32x4*)(xg + (size_t)r_ * T_LEN + c_ * 4);
                int A_ = c_ * 256 + (((r_ ^ c_) & 63) << 1);
                *(f32x2*)&lx[A_]       = mk2(v.x, v.y);
                *(f32x2*)&lx[A_ + 128] = mk2(v.z, v.w);
            }
        }
    } else {
        COMPUTE_REGS();                   // windows within [0,24)
    }
    __syncthreads();                      // bar2: full span visible; w01 done

    // ---- P3: waves 0-1 OWR+store; waves 2-3 compute ----
    if (!hiwave) {
        OWR_STORE();
    } else {
        COMPUTE_REGS();
    }
    __syncthreads();                      // bar3: w23's x reads done

    // ---- P4: waves 2-3 OWR+store ----
    if (hiwave) {
        OWR_STORE();
    }
}

extern "C" void kernel_launch(void* const* d_in, const int* in_sizes, int n_in,
                              void* d_out, int out_size, void* d_ws, size_t ws_size,
                              hipStream_t stream) {
    const float* x    = (const float*)d_in[0];
    const float* W_ih = (const float*)d_in[1];
    const float* W_hh = (const float*)d_in[2];
    const float* b_ih = (const float*)d_in[3];
    const float* b_hh = (const float*)d_in[4];
    const float* fc_w = (const float*)d_in[5];
    const float* fc_b = (const float*)d_in[6];
    float* out = (float*)d_out;

    const int B = in_sizes[0] / T_LEN;    // I == 1

    dim3 block(THREADS);
    dim3 grid((B / 64) * NCG);            // 1024 blocks = 4/CU
    rnn_stag<<<grid, block, 0, stream>>>(x, W_ih, W_hh, b_ih, b_hh,
                                         fc_w, fc_b, out);
}